// Round 16
// baseline (706.793 us; speedup 1.0000x reference)
//
#include <hip/hip_runtime.h>
#include <hip/hip_bf16.h>

// 2-layer GCN: norm (self-loops, sym D^-1/2), CSR build, GEMM, gather-aggregate.
// R15 (resubmit — broker timeout): CSR build replaced by 2-phase bucket sort.
// R14 profile: k_fill top dispatch (115-130us) with 107MB writes for 6.4MB
// payload = 16x line-thrash amplification on the random 4B scatter. Phase A
// appends (r,c) pairs into 782 streams (128-node buckets, tails cache-resident
// -> ~1x amplification); Phase B: one block per bucket, LDS histogram+scan,
// writes indptr/dinv coalesced and places edges into its contiguous 8KB csr
// slice (L1-local). Eliminates k_deg/k_dinv/k_scan1-3/k_fill. Agg + GEMM
// unchanged from R14.

static inline int cdiv(int a, int b) { return (a + b - 1) / b; }

#define BK_SHIFT 7               // 128 nodes per bucket
#define BK_CAP   4096            // slack (mean 2046, Poisson; 4096 unreachable)

__device__ inline unsigned short f2bf(float f) {
    __hip_bfloat16 b = __float2bfloat16(f);
    return *(unsigned short*)&b;
}
__device__ inline float2 bf2_to_f2(unsigned int u) {
    return make_float2(__uint_as_float(u << 16),
                       __uint_as_float(u & 0xffff0000u));
}
__device__ inline float bf_to_f(unsigned short u) {
    return __uint_as_float(((unsigned int)u) << 16);
}

// ---------------- CSR build: bucket sort ----------------

__global__ void k_initb(int* __restrict__ bcur, int nbuk) {
    int i = blockIdx.x * blockDim.x + threadIdx.x;
    if (i < nbuk) bcur[i] = 0;
}

// Phase A: append (r, c) into coarse bucket of c.
__global__ void k_bucket(const int* __restrict__ row, const int* __restrict__ col,
                         int* __restrict__ bcur, int2* __restrict__ pairs, int e) {
    int i = blockIdx.x * blockDim.x + threadIdx.x;
    if (i >= e) return;
    int c = col[i], r = row[i];
    int b = c >> BK_SHIFT;
    int p = atomicAdd(&bcur[b], 1);
    pairs[(size_t)b * BK_CAP + p] = make_int2(r, c);
}

// Exclusive scan over nbuk (<=1024) bucket counts, single block.
__global__ void k_bscan(const int* __restrict__ bcnt, int* __restrict__ bbase,
                        int nbuk) {
    __shared__ int s[1024];
    int t = threadIdx.x;
    int v = (t < nbuk) ? bcnt[t] : 0;
    s[t] = v;
    __syncthreads();
    for (int off = 1; off < 1024; off <<= 1) {
        int x = (t >= off) ? s[t - off] : 0;
        __syncthreads();
        s[t] += x;
        __syncthreads();
    }
    if (t < nbuk) bbase[t] = s[t] - v;
}

// Phase B: one block per bucket. LDS histogram -> indptr/dinv (coalesced),
// then place rows into contiguous csr slice [base, base+ne) via LDS cursors.
__global__ __launch_bounds__(256) void k_build(const int2* __restrict__ pairs,
                                               const int* __restrict__ bcnt,
                                               const int* __restrict__ bbase,
                                               int* __restrict__ indptr,
                                               float* __restrict__ dinv,
                                               int* __restrict__ csr_row,
                                               int n, int e_total) {
    __shared__ int hist[128], s[128], lcur[128];
    const int b = blockIdx.x;
    const int t = threadIdx.x;
    const int n0 = b << BK_SHIFT;
    const int nn = min(128, n - n0);
    const int ne = bcnt[b];
    const int base = bbase[b];
    const int2* pp = pairs + (size_t)b * BK_CAP;
    if (t < 128) { hist[t] = 0; lcur[t] = 0; }
    __syncthreads();
    for (int i = t; i < ne; i += 256)
        atomicAdd(&hist[pp[i].y & 127], 1);
    __syncthreads();
    if (t < 128) s[t] = hist[t];
    __syncthreads();
    for (int off = 1; off < 128; off <<= 1) {
        int x = (t < 128 && t >= off) ? s[t - off] : 0;
        __syncthreads();
        if (t < 128) s[t] += x;
        __syncthreads();
    }
    if (t < 128) s[t] -= hist[t];  // exclusive prefix
    __syncthreads();
    if (t < nn) {
        indptr[n0 + t] = base + s[t];
        dinv[n0 + t] = rsqrtf((float)(hist[t] + 1));  // +1 self-loop
    }
    if (b == 0 && t == 0) indptr[n] = e_total;
    for (int i = t; i < ne; i += 256) {
        int2 pr = pp[i];
        int c = pr.y & 127;
        int p = atomicAdd(&lcur[c], 1);
        csr_row[base + s[c] + p] = pr.x;
    }
}

// ------- dense GEMM: G[n][COUT] = dinv[n] * (X[n][128] @ W[128][COUT]), bf16 out -------

template <int COUT>
__global__ __launch_bounds__(256) void gemm_k(const float* __restrict__ X,
                                              const float* __restrict__ W,
                                              const float* __restrict__ dinv,
                                              __hip_bfloat16* __restrict__ G, int n) {
    constexpr int KT = 64;             // k-tile
    constexpr int CG = COUT / 4;       // thread groups along channels
    constexpr int MG = 256 / CG;       // thread groups along rows
    constexpr int TILE_M = MG * 4;
    __shared__ float xs[TILE_M][KT];
    __shared__ float ws[KT][COUT];
    const int t = threadIdx.x;
    const int m_base = blockIdx.x * TILE_M;
    const int tx = t % CG, ty = t / CG;
    const int c0 = tx * 4, m0 = ty * 4;
    float acc[4][4] = {};
    for (int kt = 0; kt < 128; kt += KT) {
        {   // stage W tile (KT x COUT), linear copy
            const float4* src = (const float4*)(W + (size_t)kt * COUT);
            float4* dst = (float4*)&ws[0][0];
            constexpr int NW = KT * COUT / 4 / 256;
#pragma unroll
            for (int i = 0; i < NW; i++) dst[t + i * 256] = src[t + i * 256];
        }
        {   // stage X tile (TILE_M x KT)
            float4* dst = (float4*)&xs[0][0];
            constexpr int NX = TILE_M * KT / 4 / 256;
#pragma unroll
            for (int i = 0; i < NX; i++) {
                int idx = t + i * 256;
                int m = idx >> 4, q = idx & 15;  // 16 float4 per row of KT
                int gm = m_base + m;
                float4 v = make_float4(0.f, 0.f, 0.f, 0.f);
                if (gm < n) v = ((const float4*)X)[(size_t)gm * 32 + (kt >> 2) + q];
                dst[idx] = v;
            }
        }
        __syncthreads();
#pragma unroll
        for (int k = 0; k < KT; k += 4) {
            float xr[4][4], wr[4][4];
#pragma unroll
            for (int mm = 0; mm < 4; mm++) {
                float4 v = *(const float4*)&xs[m0 + mm][k];
                xr[mm][0] = v.x; xr[mm][1] = v.y; xr[mm][2] = v.z; xr[mm][3] = v.w;
            }
#pragma unroll
            for (int kk = 0; kk < 4; kk++) {
                float4 v = *(const float4*)&ws[k + kk][c0];
                wr[kk][0] = v.x; wr[kk][1] = v.y; wr[kk][2] = v.z; wr[kk][3] = v.w;
            }
#pragma unroll
            for (int kk = 0; kk < 4; kk++)
#pragma unroll
                for (int mm = 0; mm < 4; mm++)
#pragma unroll
                    for (int cc = 0; cc < 4; cc++)
                        acc[mm][cc] = fmaf(xr[mm][kk], wr[kk][cc], acc[mm][cc]);
        }
        __syncthreads();
    }
#pragma unroll
    for (int mm = 0; mm < 4; mm++) {
        int gm = m_base + m0 + mm;
        if (gm < n) {
            float dv = dinv[gm];
            ushort4 o;
            o.x = f2bf(dv * acc[mm][0]); o.y = f2bf(dv * acc[mm][1]);
            o.z = f2bf(dv * acc[mm][2]); o.w = f2bf(dv * acc[mm][3]);
            *(ushort4*)&G[(size_t)gm * COUT + c0] = o;
        }
    }
}

// -------- aggregation: grid-stride persistent waves, one node at a time --------
// s = g[c] + sum g[r]; out = dinv[c]*s + b. 8 gathers in flight, 8 accumulators.

// C=128: lane handles 2 channels (packed bf16x2 = 4B gather). relu.
__global__ __launch_bounds__(256) void k_agg128(const __hip_bfloat16* __restrict__ g,
                                                const int* __restrict__ indptr,
                                                const int* __restrict__ csr_row,
                                                const float* __restrict__ dinv,
                                                const float* __restrict__ bias,
                                                float* __restrict__ out, int n) {
    const int lane = threadIdx.x & 63;
    const int wid0 = (blockIdx.x * blockDim.x + threadIdx.x) >> 6;
    const int nw = (gridDim.x * blockDim.x) >> 6;
    const unsigned int* gp = (const unsigned int*)g;  // 2 bf16 per uint, 64/row
    const float2 b = ((const float2*)bias)[lane];
    for (int wid = wid0; wid < n; wid += nw) {
        float2 a[8];
#pragma unroll
        for (int k = 0; k < 8; k++) a[k] = make_float2(0.f, 0.f);
        {
            float2 v = bf2_to_f2(gp[(size_t)wid * 64 + lane]);  // self (g[c])
            a[0] = v;
        }
        int e = indptr[wid], e1 = indptr[wid + 1];
        for (; e + 8 <= e1; e += 8) {
            int r[8];
#pragma unroll
            for (int k = 0; k < 8; k++) r[k] = csr_row[e + k];
#pragma unroll
            for (int k = 0; k < 8; k++) {
                float2 v = bf2_to_f2(gp[(size_t)r[k] * 64 + lane]);
                a[k].x += v.x;
                a[k].y += v.y;
            }
        }
        for (; e < e1; e++) {
            float2 v = bf2_to_f2(gp[(size_t)csr_row[e] * 64 + lane]);
            a[0].x += v.x;
            a[0].y += v.y;
        }
        float dv = dinv[wid];
        float sx = ((a[0].x + a[1].x) + (a[2].x + a[3].x)) +
                   ((a[4].x + a[5].x) + (a[6].x + a[7].x));
        float sy = ((a[0].y + a[1].y) + (a[2].y + a[3].y)) +
                   ((a[4].y + a[5].y) + (a[6].y + a[7].y));
        ((float2*)(out + (size_t)wid * 128))[lane] =
            make_float2(fmaxf(fmaf(dv, sx, b.x), 0.f),
                        fmaxf(fmaf(dv, sy, b.y), 0.f));
    }
}

// C=64: lane handles 1 channel (2B bf16 gather; 128B/row = 1 cache line).
__global__ __launch_bounds__(256) void k_agg64(const __hip_bfloat16* __restrict__ g,
                                               const int* __restrict__ indptr,
                                               const int* __restrict__ csr_row,
                                               const float* __restrict__ dinv,
                                               const float* __restrict__ bias,
                                               float* __restrict__ out, int n) {
    const int lane = threadIdx.x & 63;
    const int wid0 = (blockIdx.x * blockDim.x + threadIdx.x) >> 6;
    const int nw = (gridDim.x * blockDim.x) >> 6;
    const unsigned short* gp = (const unsigned short*)g;
    const float b = bias[lane];
    for (int wid = wid0; wid < n; wid += nw) {
        float a[8];
#pragma unroll
        for (int k = 0; k < 8; k++) a[k] = 0.f;
        a[0] = bf_to_f(gp[(size_t)wid * 64 + lane]);  // self
        int e = indptr[wid], e1 = indptr[wid + 1];
        for (; e + 8 <= e1; e += 8) {
            int r[8];
#pragma unroll
            for (int k = 0; k < 8; k++) r[k] = csr_row[e + k];
#pragma unroll
            for (int k = 0; k < 8; k++)
                a[k] += bf_to_f(gp[(size_t)r[k] * 64 + lane]);
        }
        for (; e < e1; e++)
            a[0] += bf_to_f(gp[(size_t)csr_row[e] * 64 + lane]);
        float s = ((a[0] + a[1]) + (a[2] + a[3])) + ((a[4] + a[5]) + (a[6] + a[7]));
        out[(size_t)wid * 64 + lane] = fmaf(dinv[wid], s, b);
    }
}

// ---------------- launch ----------------

extern "C" void kernel_launch(void* const* d_in, const int* in_sizes, int n_in,
                              void* d_out, int out_size, void* d_ws, size_t ws_size,
                              hipStream_t stream) {
    const float* x  = (const float*)d_in[0];
    const int* ei   = (const int*)d_in[1];
    const float* W1 = (const float*)d_in[2];
    const float* b1 = (const float*)d_in[3];
    const float* W2 = (const float*)d_in[4];
    const float* b2 = (const float*)d_in[5];
    float* out = (float*)d_out;

    const int N = in_sizes[0] / 128;
    const int E = in_sizes[1] / 2;
    const int* row = ei;       // edge_index[0] = source
    const int* col = ei + E;   // edge_index[1] = target
    const int NBUK = cdiv(N, 1 << BK_SHIFT);  // 782 buckets of 128 nodes

    char* p = (char*)d_ws;
    auto carve = [&](size_t bytes) -> void* {
        void* r = (void*)p;
        p += (bytes + 255) & ~(size_t)255;
        return r;
    };
    int*   bcur     = (int*)carve((size_t)NBUK * 4);
    int*   bbase    = (int*)carve((size_t)NBUK * 4);
    int*   indptr   = (int*)carve((size_t)(N + 1) * 4);
    float* dinv     = (float*)carve((size_t)N * 4);
    int*   csr_row  = (int*)carve((size_t)E * 4);
    int2*  pairs    = (int2*)carve((size_t)NBUK * BK_CAP * 8);         // 25.6MB
    __hip_bfloat16* g1 = (__hip_bfloat16*)carve((size_t)N * 128 * 2);  // dinv*x@W1
    float* h1          = (float*)carve((size_t)N * 128 * 4);
    __hip_bfloat16* g2 = (__hip_bfloat16*)carve((size_t)N * 64 * 2);   // dinv*h1@W2

    const int AGG_BLOCKS = 2048;  // 8192 persistent waves, ~12 nodes each

    // CSR build: bucket sort
    k_initb<<<cdiv(NBUK, 256), 256, 0, stream>>>(bcur, NBUK);
    k_bucket<<<cdiv(E, 256), 256, 0, stream>>>(row, col, bcur, pairs, E);
    k_bscan<<<1, 1024, 0, stream>>>(bcur, bbase, NBUK);
    k_build<<<NBUK, 256, 0, stream>>>(pairs, bcur, bbase, indptr, dinv,
                                      csr_row, N, E);

    // layer 1: g1 = bf16(dinv * x@W1) ; h1 = relu(dinv*(g1_self+sum) + b1)
    gemm_k<128><<<cdiv(N, 32), 256, 0, stream>>>(x, W1, dinv, g1, N);
    k_agg128<<<AGG_BLOCKS, 256, 0, stream>>>(g1, indptr, csr_row, dinv, b1, h1, N);
    // layer 2: g2 = bf16(dinv * h1@W2) ; out = dinv*(g2_self+sum) + b2
    gemm_k<64><<<cdiv(N, 64), 256, 0, stream>>>(h1, W2, dinv, g2, N);
    k_agg64<<<AGG_BLOCKS, 256, 0, stream>>>(g2, indptr, csr_row, dinv, b2, out, N);
}